// Round 11
// baseline (189.943 us; speedup 1.0000x reference)
//
#include <hip/hip_runtime.h>
#include <hip/hip_bf16.h>
#include <math.h>

#define N_TOK 4096
#define D_DIM 1024
#define R_REL 92
#define T_TAG 32
#define E_EDGE 8192
#define SELF_R 127
#define GRID_ITEMS 192   // 32 self chunks + up to 160 dep chunks

// ws int layout:
//   [0..127] cnt_rel | [256..383] off_rel | [384] n_items
//   [512..1023] items (r<<16|chunk); [0..31] self | [1024..9215] sorted tokens
//   [17408..21504] tok_off | [22528..30719] tok_list (positions by token)
// bf16 scratch at ws+32768 ints: rows [0..8191] dep, [8192..12287] self
// bf16 xb after scratch: 4096x1024

typedef short bf16x8 __attribute__((ext_vector_type(8)));
typedef float f32x4 __attribute__((ext_vector_type(4)));

union Pk8 { uint4 q; unsigned short s[8]; };
union Pk4 { uint2 d; unsigned short s[4]; };

__device__ __forceinline__ unsigned short f2bf(float f) {
    union { __hip_bfloat16 b; unsigned short u; } c;
    c.b = __float2bfloat16(f);
    return c.u;
}
__device__ __forceinline__ float bf2f(unsigned short u) {
    return __uint_as_float(((unsigned)u) << 16);
}
__device__ __forceinline__ void gload_lds16(const void* g, void* l) {
    __builtin_amdgcn_global_load_lds(
        (const __attribute__((address_space(1))) unsigned int*)g,
        (__attribute__((address_space(3))) unsigned int*)l, 16, 0, 0);
}

// block 0: edge setup; blocks 1..512: x -> bf16 convert
__global__ __launch_bounds__(1024) void k_prep(const int* __restrict__ rel,
                                               const int* __restrict__ tokv,
                                               const float* __restrict__ x,
                                               int* __restrict__ ws,
                                               unsigned short* __restrict__ xb) {
    int t = threadIdx.x;
    if (blockIdx.x > 0) {
        size_t base = ((size_t)(blockIdx.x - 1) * 1024 + t) * 8;
        float4 v0 = *(const float4*)(x + base);
        float4 v1 = *(const float4*)(x + base + 4);
        Pk8 u;
        u.s[0] = f2bf(v0.x); u.s[1] = f2bf(v0.y);
        u.s[2] = f2bf(v0.z); u.s[3] = f2bf(v0.w);
        u.s[4] = f2bf(v1.x); u.s[5] = f2bf(v1.y);
        u.s[6] = f2bf(v1.z); u.s[7] = f2bf(v1.w);
        *(uint4*)(xb + base) = u.q;
        return;
    }
    __shared__ int cnt[128], offL[128], cur[128];
    __shared__ int sh[128];
    __shared__ int wsum[16];
    __shared__ int tcnt[4096], toff[4096];
    int lane = t & 63, wid = t >> 6;
    if (t < 128) { cnt[t] = 0; cur[t] = 0; }
    #pragma unroll
    for (int i = 0; i < 4; ++i) tcnt[i * 1024 + t] = 0;
    __syncthreads();
    int er[8], et[8];
    #pragma unroll
    for (int i = 0; i < 8; ++i) {
        er[i] = rel[i * 1024 + t];
        et[i] = tokv[i * 1024 + t];
        atomicAdd(&cnt[er[i]], 1);
        atomicAdd(&tcnt[et[i]], 1);
    }
    __syncthreads();
    int c = (t < 128) ? cnt[t] : 0;
    int v = c;
    if (t < 128) sh[t] = v;
    __syncthreads();
    for (int st = 1; st < 128; st <<= 1) {
        int add = (t >= st && t < 128) ? sh[t - st] : 0;
        __syncthreads();
        if (t < 128) { v += add; sh[t] = v; }
        __syncthreads();
    }
    if (t < 128) { offL[t] = v - c; ws[256 + t] = v - c; ws[t] = c; }
    int ch = (t < R_REL) ? ((c + 127) >> 7) : 0;
    int v2 = ch;
    if (t < 128) sh[t] = v2;
    __syncthreads();
    for (int st = 1; st < 128; st <<= 1) {
        int add = (t >= st && t < 128) ? sh[t - st] : 0;
        __syncthreads();
        if (t < 128) { v2 += add; sh[t] = v2; }
        __syncthreads();
    }
    if (t < 32) ws[512 + t] = (SELF_R << 16) | t;
    if (t < R_REL) {
        int excl = v2 - ch;
        for (int j = 0; j < ch; ++j)
            ws[512 + 32 + excl + j] = (t << 16) | j;
    }
    if (t == 127) ws[384] = 32 + v2;
    // token-count scan via wave shfl scans
    int s0 = tcnt[4 * t + 0], s1 = tcnt[4 * t + 1];
    int s2 = tcnt[4 * t + 2], s3 = tcnt[4 * t + 3];
    int sum4 = s0 + s1 + s2 + s3;
    int vv = sum4;
    #pragma unroll
    for (int d = 1; d < 64; d <<= 1) {
        int n = __shfl_up(vv, d);
        if (lane >= d) vv += n;
    }
    if (lane == 63) wsum[wid] = vv;
    __syncthreads();
    if (wid == 0) {
        int wv = (lane < 16) ? wsum[lane] : 0;
        #pragma unroll
        for (int d = 1; d < 16; d <<= 1) {
            int n = __shfl_up(wv, d);
            if (lane >= d) wv += n;
        }
        if (lane < 16) wsum[lane] = wv;
    }
    __syncthreads();
    int base = (wid > 0) ? wsum[wid - 1] : 0;
    int incl = base + vv;
    int ex = incl - sum4;
    toff[4 * t + 0] = ex;
    toff[4 * t + 1] = ex + s0;
    toff[4 * t + 2] = ex + s0 + s1;
    toff[4 * t + 3] = ex + s0 + s1 + s2;
    ws[17408 + 4 * t + 0] = ex;
    ws[17408 + 4 * t + 1] = ex + s0;
    ws[17408 + 4 * t + 2] = ex + s0 + s1;
    ws[17408 + 4 * t + 3] = ex + s0 + s1 + s2;
    if (t == 1023) ws[17408 + 4096] = incl;
    __syncthreads();
    #pragma unroll
    for (int i = 0; i < 4; ++i) tcnt[i * 1024 + t] = 0;
    __syncthreads();
    #pragma unroll
    for (int i = 0; i < 8; ++i) {
        int pos = offL[er[i]] + atomicAdd(&cur[er[i]], 1);
        ws[1024 + pos] = et[i];
        int q = toff[et[i]] + atomicAdd(&tcnt[et[i]], 1);
        ws[22528 + q] = pos;
    }
}

// Fused grouped GEMM (R8 config): 128x128xBK=64, 8 waves, dbuf LDS,
// A via global_load_lds from bf16 xb (swizzle in source addr), B reg-staged,
// one barrier per K-step, dense bf16 scratch output.
__global__ __launch_bounds__(512, 4) void k_fused(const float* __restrict__ Wself,
                                                  const float* __restrict__ bself,
                                                  const float* __restrict__ Wst,
                                                  const float* __restrict__ Bst,
                                                  const int* __restrict__ ws,
                                                  const unsigned short* __restrict__ xb,
                                                  unsigned short* __restrict__ scratch) {
    if ((int)blockIdx.x >= ws[384]) return;
    int item = ws[512 + blockIdx.x];
    int r = item >> 16, chunk = item & 0xFFFF;
    int m0 = chunk * 128;
    int valid;
    const float* Wbase;
    const float* bias;
    bool is_self = (r == SELF_R);
    int off0 = 0;
    if (is_self) {
        valid = 128;
        Wbase = Wself;
        bias = bself;
    } else {
        int cnt = ws[r];
        off0 = ws[256 + r];
        valid = cnt - m0; if (valid > 128) valid = 128;
        Wbase = Wst + (size_t)r * D_DIM * D_DIM;
        bias = Bst + (size_t)r * D_DIM;
    }
    int srow_base = is_self ? (8192 + m0) : (off0 + m0);

    __shared__ unsigned short Al[2][8192];
    __shared__ unsigned short Bl[2][8192];
    __shared__ int toks[128];
    int t = threadIdx.x;
    if (t < 128) {
        int tok;
        if (is_self) tok = m0 + t;
        else tok = (t < valid) ? ws[1024 + off0 + m0 + t] : 0;
        toks[t] = tok;
    }
    __syncthreads();

    int gn0 = blockIdx.y * 128;
    int wid = t >> 6, l = t & 63;
    int lr = l & 15, lg = l >> 4;
    int wm = (wid >> 2) * 64, wn = (wid & 3) * 32;

    int row0 = wid * 16 + (l >> 3);
    int row1 = row0 + 8;
    const char* ga0 = (const char*)(xb + (size_t)toks[row0] * D_DIM) +
                      (((l & 7) * 16) ^ ((row0 & 7) << 4));
    const char* ga1 = (const char*)(xb + (size_t)toks[row1] * D_DIM) +
                      (((l & 7) * 16) ^ ((row1 & 7) << 4));

    int bcol = t & 127, bkq = t >> 7;
    const float* wp = Wbase + (size_t)bkq * 16 * D_DIM + gn0 + bcol;
    int bswz = (bcol & 7) << 4;
    int bb0 = bcol * 128 + ((bkq * 32) ^ bswz);
    int bb1 = bcol * 128 + ((bkq * 32 + 16) ^ bswz);

    float pb[16];
    // ---- prologue: stage tile 0 into buf 0 ----
    gload_lds16(ga0, (char*)Al[0] + wid * 2048);
    gload_lds16(ga1, (char*)Al[0] + wid * 2048 + 1024);
    ga0 += 128; ga1 += 128;
    #pragma unroll
    for (int i = 0; i < 16; ++i) pb[i] = wp[(size_t)i * D_DIM];
    {
        Pk8 u0, u1;
        #pragma unroll
        for (int i = 0; i < 8; ++i) { u0.s[i] = f2bf(pb[i]); u1.s[i] = f2bf(pb[8 + i]); }
        *(uint4*)((char*)Bl[0] + bb0) = u0.q;
        *(uint4*)((char*)Bl[0] + bb1) = u1.q;
    }
    __syncthreads();

    f32x4 acc[4][2] = {};
    int cur = 0;
    for (int k0 = 0; k0 < D_DIM; k0 += 64) {
        bool pf = (k0 + 64 < D_DIM);
        int nxt = cur ^ 1;
        if (pf) {                        // issue next-tile loads; fly over MFMA
            gload_lds16(ga0, (char*)Al[nxt] + wid * 2048);
            gload_lds16(ga1, (char*)Al[nxt] + wid * 2048 + 1024);
            ga0 += 128; ga1 += 128;
            #pragma unroll
            for (int i = 0; i < 16; ++i)
                pb[i] = wp[(size_t)(k0 + 64 + i) * D_DIM];
        }
        const char* Ac = (const char*)Al[cur];
        const char* Bc = (const char*)Bl[cur];
        #pragma unroll
        for (int kk = 0; kk < 2; ++kk) {
            int koff = kk * 64 + lg * 16;
            int sw = (lr & 7) << 4;
            bf16x8 af[4], bfr[2];
            #pragma unroll
            for (int mi = 0; mi < 4; ++mi)
                af[mi] = *(const bf16x8*)(Ac + (wm + mi * 16 + lr) * 128 + (koff ^ sw));
            #pragma unroll
            for (int ni = 0; ni < 2; ++ni)
                bfr[ni] = *(const bf16x8*)(Bc + (wn + ni * 16 + lr) * 128 + (koff ^ sw));
            #pragma unroll
            for (int mi = 0; mi < 4; ++mi)
                #pragma unroll
                for (int ni = 0; ni < 2; ++ni)
                    acc[mi][ni] = __builtin_amdgcn_mfma_f32_16x16x32_bf16(
                        af[mi], bfr[ni], acc[mi][ni], 0, 0, 0);
        }
        if (pf) {                        // cvt+write B(t+1) into other buffer
            Pk8 u0, u1;
            #pragma unroll
            for (int i = 0; i < 8; ++i) { u0.s[i] = f2bf(pb[i]); u1.s[i] = f2bf(pb[8 + i]); }
            *(uint4*)((char*)Bl[nxt] + bb0) = u0.q;
            *(uint4*)((char*)Bl[nxt] + bb1) = u1.q;
        }
        __syncthreads();                 // one barrier per K-step
        cur = nxt;
    }
    float bb[2];
    bb[0] = bias[gn0 + wn + lr];
    bb[1] = bias[gn0 + wn + 16 + lr];
    #pragma unroll
    for (int mi = 0; mi < 4; ++mi)
        #pragma unroll
        for (int j = 0; j < 4; ++j) {
            int rl = wm + mi * 16 + lg * 4 + j;
            if (rl < valid) {
                unsigned short* dst = scratch +
                    (size_t)(srow_base + rl) * D_DIM + gn0 + wn + lr;
                dst[0]  = f2bf(acc[mi][0][j] + bb[0]);
                dst[16] = f2bf(acc[mi][1][j] + bb[1]);
            }
        }
}

// Fused reduce + tag head: per 64-k chunk, gather-reduce h slice from scratch
// (self + deps, f32 accum, relu), write h f32 (output), cvt into swizzled LDS,
// then tag MFMA. Epilogue: log_softmax. 128 blocks x 128 threads x 32 tokens.
__global__ __launch_bounds__(128) void k_redtag(const int* __restrict__ ws,
                                                const unsigned short* __restrict__ scratch,
                                                const float* __restrict__ Wt,
                                                const float* __restrict__ bt,
                                                float* __restrict__ out_h,
                                                float* __restrict__ out_tag) {
    __shared__ unsigned short Al[32 * 64];   // [row][k] bf16, swizzled
    __shared__ unsigned short Bl[32 * 64];   // [tag][k] bf16, swizzled
    __shared__ int j0s[32], j1s[32];
    char* Alb = (char*)Al;
    char* Blb = (char*)Bl;
    int tok0 = blockIdx.x * 32;
    int t = threadIdx.x;
    if (t < 32) {
        j0s[t] = ws[17408 + tok0 + t];
        j1s[t] = ws[17408 + tok0 + t + 1];
    }
    int w = t >> 6, l = t & 63, lr = l & 15, lg = l >> 4;
    int wm = w * 16;
    int row = t >> 2, c16 = (t & 3) * 16;     // reduce map: 32 rows x 4 thr
    int bn = t & 31, kh = (t >> 5) & 3;       // Wt map: 32 tags x 4 k-quarters
    f32x4 acc[2] = {};
    for (int k0 = 0; k0 < D_DIM; k0 += 64) {
        __syncthreads();                       // LDS free (covers j0s on iter 0)
        {   // ---- gather-reduce 16 cols of one token row ----
            int tok = tok0 + row;
            const unsigned short* sp =
                scratch + (size_t)(8192 + tok) * D_DIM + k0 + c16;
            Pk8 v0, v1;
            v0.q = *(const uint4*)sp;
            v1.q = *(const uint4*)(sp + 8);
            float a[16];
            #pragma unroll
            for (int i = 0; i < 8; ++i) {
                a[i] = bf2f(v0.s[i]);
                a[8 + i] = bf2f(v1.s[i]);
            }
            for (int j = j0s[row]; j < j1s[row]; ++j) {
                int p = ws[22528 + j];
                const unsigned short* dp =
                    scratch + (size_t)p * D_DIM + k0 + c16;
                Pk8 d0, d1;
                d0.q = *(const uint4*)dp;
                d1.q = *(const uint4*)(dp + 8);
                #pragma unroll
                for (int i = 0; i < 8; ++i) {
                    a[i] += bf2f(d0.s[i]);
                    a[8 + i] += bf2f(d1.s[i]);
                }
            }
            #pragma unroll
            for (int i = 0; i < 16; ++i) a[i] = fmaxf(a[i], 0.f);
            float* hp = out_h + (size_t)tok * D_DIM + k0 + c16;
            #pragma unroll
            for (int q = 0; q < 4; ++q) {
                float4 o;
                o.x = a[4 * q]; o.y = a[4 * q + 1];
                o.z = a[4 * q + 2]; o.w = a[4 * q + 3];
                *(float4*)(hp + 4 * q) = o;
            }
            Pk8 u0, u1;
            #pragma unroll
            for (int i = 0; i < 8; ++i) {
                u0.s[i] = f2bf(a[i]);
                u1.s[i] = f2bf(a[8 + i]);
            }
            int sw = (row & 7) << 4;
            *(uint4*)(Alb + row * 128 + ((c16 * 2) ^ sw)) = u0.q;
            *(uint4*)(Alb + row * 128 + ((c16 * 2 + 16) ^ sw)) = u1.q;
        }
        {   // ---- stage Wt chunk ----
            int swb = (bn & 7) << 4;
            Pk8 u;
            #pragma unroll
            for (int i = 0; i < 8; ++i)
                u.s[i] = f2bf(Wt[(size_t)(k0 + kh * 16 + i) * T_TAG + bn]);
            *(uint4*)(Blb + bn * 128 + ((kh * 32) ^ swb)) = u.q;
            #pragma unroll
            for (int i = 0; i < 8; ++i)
                u.s[i] = f2bf(Wt[(size_t)(k0 + kh * 16 + 8 + i) * T_TAG + bn]);
            *(uint4*)(Blb + bn * 128 + ((kh * 32 + 16) ^ swb)) = u.q;
        }
        __syncthreads();
        #pragma unroll
        for (int kk = 0; kk < 2; ++kk) {
            int koff = kk * 64 + lg * 16;
            int sw = (lr & 7) << 4;
            bf16x8 af = *(const bf16x8*)(Alb + (wm + lr) * 128 + (koff ^ sw));
            #pragma unroll
            for (int ni = 0; ni < 2; ++ni) {
                bf16x8 bfr = *(const bf16x8*)(Blb + (ni * 16 + lr) * 128 + (koff ^ sw));
                acc[ni] = __builtin_amdgcn_mfma_f32_16x16x32_bf16(
                    af, bfr, acc[ni], 0, 0, 0);
            }
        }
    }
    float bt0 = bt[lr], bt1 = bt[16 + lr];
    #pragma unroll
    for (int j = 0; j < 4; ++j) {
        float v0 = acc[0][j] + bt0;
        float v1 = acc[1][j] + bt1;
        float m = fmaxf(v0, v1);
        #pragma unroll
        for (int s = 1; s < 16; s <<= 1) m = fmaxf(m, __shfl_xor(m, s));
        float sum = expf(v0 - m) + expf(v1 - m);
        #pragma unroll
        for (int s = 1; s < 16; s <<= 1) sum += __shfl_xor(sum, s);
        float lse = m + logf(sum);
        int rowo = tok0 + wm + lg * 4 + j;
        out_tag[(size_t)rowo * T_TAG + lr] = v0 - lse;
        out_tag[(size_t)rowo * T_TAG + 16 + lr] = v1 - lse;
    }
}

extern "C" void kernel_launch(void* const* d_in, const int* in_sizes, int n_in,
                              void* d_out, int out_size, void* d_ws, size_t ws_size,
                              hipStream_t stream) {
    const float* x     = (const float*)d_in[0];
    const float* Wself = (const float*)d_in[1];
    const float* bself = (const float*)d_in[2];
    const float* Wst   = (const float*)d_in[3];
    const float* Bst   = (const float*)d_in[4];
    const float* Wtag  = (const float*)d_in[5];
    const float* btag  = (const float*)d_in[6];
    const int*   etok  = (const int*)d_in[7];
    const int*   erel  = (const int*)d_in[8];
    float* out_tag = (float*)d_out;
    float* out_h   = (float*)d_out + (size_t)N_TOK * T_TAG;
    int* ws = (int*)d_ws;
    unsigned short* scratch = (unsigned short*)((int*)d_ws + 32768);
    unsigned short* xb = scratch + (size_t)12288 * 1024;

    k_prep<<<513, 1024, 0, stream>>>(erel, etok, x, ws, xb);
    k_fused<<<dim3(GRID_ITEMS, D_DIM / 128), 512, 0, stream>>>(
        Wself, bself, Wst, Bst, ws, xb, scratch);
    k_redtag<<<N_TOK / 32, 128, 0, stream>>>(ws, scratch, Wtag, btag, out_h, out_tag);
}

// Round 12
// 144.445 us; speedup vs baseline: 1.3150x; 1.3150x over previous
//
#include <hip/hip_runtime.h>
#include <hip/hip_bf16.h>
#include <math.h>

#define N_TOK 4096
#define D_DIM 1024
#define R_REL 92
#define T_TAG 32
#define E_EDGE 8192
#define SELF_R 127
#define GRID_ITEMS 192   // 32 self chunks + up to 160 dep chunks

// ws int layout:
//   [0..127] cnt_rel | [256..383] off_rel | [384] n_items
//   [512..1023] items (r<<16|chunk); [0..31] self | [1024..9215] sorted tokens
//   [17408..21504] tok_off | [22528..30719] tok_list (positions by token)
// bf16 scratch at ws+32768 ints: rows [0..8191] dep, [8192..12287] self
// bf16 xb after scratch: 4096x1024

typedef short bf16x8 __attribute__((ext_vector_type(8)));
typedef float f32x4 __attribute__((ext_vector_type(4)));

union Pk8 { uint4 q; unsigned short s[8]; };
union Pk4 { uint2 d; unsigned short s[4]; };

__device__ __forceinline__ unsigned short f2bf(float f) {
    union { __hip_bfloat16 b; unsigned short u; } c;
    c.b = __float2bfloat16(f);
    return c.u;
}
__device__ __forceinline__ float bf2f(unsigned short u) {
    return __uint_as_float(((unsigned)u) << 16);
}
__device__ __forceinline__ void gload_lds16(const void* g, void* l) {
    __builtin_amdgcn_global_load_lds(
        (const __attribute__((address_space(1))) unsigned int*)g,
        (__attribute__((address_space(3))) unsigned int*)l, 16, 0, 0);
}

// block 0: edge setup; blocks 1..512: x -> bf16 convert
__global__ __launch_bounds__(1024) void k_prep(const int* __restrict__ rel,
                                               const int* __restrict__ tokv,
                                               const float* __restrict__ x,
                                               int* __restrict__ ws,
                                               unsigned short* __restrict__ xb) {
    int t = threadIdx.x;
    if (blockIdx.x > 0) {
        size_t base = ((size_t)(blockIdx.x - 1) * 1024 + t) * 8;
        float4 v0 = *(const float4*)(x + base);
        float4 v1 = *(const float4*)(x + base + 4);
        Pk8 u;
        u.s[0] = f2bf(v0.x); u.s[1] = f2bf(v0.y);
        u.s[2] = f2bf(v0.z); u.s[3] = f2bf(v0.w);
        u.s[4] = f2bf(v1.x); u.s[5] = f2bf(v1.y);
        u.s[6] = f2bf(v1.z); u.s[7] = f2bf(v1.w);
        *(uint4*)(xb + base) = u.q;
        return;
    }
    __shared__ int cnt[128], offL[128], cur[128];
    __shared__ int sh[128];
    __shared__ int wsum[16];
    __shared__ int tcnt[4096], toff[4096];
    int lane = t & 63, wid = t >> 6;
    if (t < 128) { cnt[t] = 0; cur[t] = 0; }
    #pragma unroll
    for (int i = 0; i < 4; ++i) tcnt[i * 1024 + t] = 0;
    __syncthreads();
    int er[8], et[8];
    #pragma unroll
    for (int i = 0; i < 8; ++i) {
        er[i] = rel[i * 1024 + t];
        et[i] = tokv[i * 1024 + t];
        atomicAdd(&cnt[er[i]], 1);
        atomicAdd(&tcnt[et[i]], 1);
    }
    __syncthreads();
    int c = (t < 128) ? cnt[t] : 0;
    int v = c;
    if (t < 128) sh[t] = v;
    __syncthreads();
    for (int st = 1; st < 128; st <<= 1) {
        int add = (t >= st && t < 128) ? sh[t - st] : 0;
        __syncthreads();
        if (t < 128) { v += add; sh[t] = v; }
        __syncthreads();
    }
    if (t < 128) { offL[t] = v - c; ws[256 + t] = v - c; ws[t] = c; }
    int ch = (t < R_REL) ? ((c + 127) >> 7) : 0;
    int v2 = ch;
    if (t < 128) sh[t] = v2;
    __syncthreads();
    for (int st = 1; st < 128; st <<= 1) {
        int add = (t >= st && t < 128) ? sh[t - st] : 0;
        __syncthreads();
        if (t < 128) { v2 += add; sh[t] = v2; }
        __syncthreads();
    }
    if (t < 32) ws[512 + t] = (SELF_R << 16) | t;
    if (t < R_REL) {
        int excl = v2 - ch;
        for (int j = 0; j < ch; ++j)
            ws[512 + 32 + excl + j] = (t << 16) | j;
    }
    if (t == 127) ws[384] = 32 + v2;
    // token-count scan via wave shfl scans
    int s0 = tcnt[4 * t + 0], s1 = tcnt[4 * t + 1];
    int s2 = tcnt[4 * t + 2], s3 = tcnt[4 * t + 3];
    int sum4 = s0 + s1 + s2 + s3;
    int vv = sum4;
    #pragma unroll
    for (int d = 1; d < 64; d <<= 1) {
        int n = __shfl_up(vv, d);
        if (lane >= d) vv += n;
    }
    if (lane == 63) wsum[wid] = vv;
    __syncthreads();
    if (wid == 0) {
        int wv = (lane < 16) ? wsum[lane] : 0;
        #pragma unroll
        for (int d = 1; d < 16; d <<= 1) {
            int n = __shfl_up(wv, d);
            if (lane >= d) wv += n;
        }
        if (lane < 16) wsum[lane] = wv;
    }
    __syncthreads();
    int base = (wid > 0) ? wsum[wid - 1] : 0;
    int incl = base + vv;
    int ex = incl - sum4;
    toff[4 * t + 0] = ex;
    toff[4 * t + 1] = ex + s0;
    toff[4 * t + 2] = ex + s0 + s1;
    toff[4 * t + 3] = ex + s0 + s1 + s2;
    ws[17408 + 4 * t + 0] = ex;
    ws[17408 + 4 * t + 1] = ex + s0;
    ws[17408 + 4 * t + 2] = ex + s0 + s1;
    ws[17408 + 4 * t + 3] = ex + s0 + s1 + s2;
    if (t == 1023) ws[17408 + 4096] = incl;
    __syncthreads();
    #pragma unroll
    for (int i = 0; i < 4; ++i) tcnt[i * 1024 + t] = 0;
    __syncthreads();
    #pragma unroll
    for (int i = 0; i < 8; ++i) {
        int pos = offL[er[i]] + atomicAdd(&cur[er[i]], 1);
        ws[1024 + pos] = et[i];
        int q = toff[et[i]] + atomicAdd(&tcnt[et[i]], 1);
        ws[22528 + q] = pos;
    }
}

// Fused grouped GEMM (R8 config): 128x128xBK=64, 8 waves, dbuf LDS,
// A via global_load_lds from bf16 xb (swizzle in source addr), B reg-staged,
// one barrier per K-step, dense bf16 scratch output.
__global__ __launch_bounds__(512, 4) void k_fused(const float* __restrict__ Wself,
                                                  const float* __restrict__ bself,
                                                  const float* __restrict__ Wst,
                                                  const float* __restrict__ Bst,
                                                  const int* __restrict__ ws,
                                                  const unsigned short* __restrict__ xb,
                                                  unsigned short* __restrict__ scratch) {
    if ((int)blockIdx.x >= ws[384]) return;
    int item = ws[512 + blockIdx.x];
    int r = item >> 16, chunk = item & 0xFFFF;
    int m0 = chunk * 128;
    int valid;
    const float* Wbase;
    const float* bias;
    bool is_self = (r == SELF_R);
    int off0 = 0;
    if (is_self) {
        valid = 128;
        Wbase = Wself;
        bias = bself;
    } else {
        int cnt = ws[r];
        off0 = ws[256 + r];
        valid = cnt - m0; if (valid > 128) valid = 128;
        Wbase = Wst + (size_t)r * D_DIM * D_DIM;
        bias = Bst + (size_t)r * D_DIM;
    }
    int srow_base = is_self ? (8192 + m0) : (off0 + m0);

    __shared__ unsigned short Al[2][8192];
    __shared__ unsigned short Bl[2][8192];
    __shared__ int toks[128];
    int t = threadIdx.x;
    if (t < 128) {
        int tok;
        if (is_self) tok = m0 + t;
        else tok = (t < valid) ? ws[1024 + off0 + m0 + t] : 0;
        toks[t] = tok;
    }
    __syncthreads();

    int gn0 = blockIdx.y * 128;
    int wid = t >> 6, l = t & 63;
    int lr = l & 15, lg = l >> 4;
    int wm = (wid >> 2) * 64, wn = (wid & 3) * 32;

    int row0 = wid * 16 + (l >> 3);
    int row1 = row0 + 8;
    const char* ga0 = (const char*)(xb + (size_t)toks[row0] * D_DIM) +
                      (((l & 7) * 16) ^ ((row0 & 7) << 4));
    const char* ga1 = (const char*)(xb + (size_t)toks[row1] * D_DIM) +
                      (((l & 7) * 16) ^ ((row1 & 7) << 4));

    int bcol = t & 127, bkq = t >> 7;
    const float* wp = Wbase + (size_t)bkq * 16 * D_DIM + gn0 + bcol;
    int bswz = (bcol & 7) << 4;
    int bb0 = bcol * 128 + ((bkq * 32) ^ bswz);
    int bb1 = bcol * 128 + ((bkq * 32 + 16) ^ bswz);

    float pb[16];
    // ---- prologue: stage tile 0 into buf 0 ----
    gload_lds16(ga0, (char*)Al[0] + wid * 2048);
    gload_lds16(ga1, (char*)Al[0] + wid * 2048 + 1024);
    ga0 += 128; ga1 += 128;
    #pragma unroll
    for (int i = 0; i < 16; ++i) pb[i] = wp[(size_t)i * D_DIM];
    {
        Pk8 u0, u1;
        #pragma unroll
        for (int i = 0; i < 8; ++i) { u0.s[i] = f2bf(pb[i]); u1.s[i] = f2bf(pb[8 + i]); }
        *(uint4*)((char*)Bl[0] + bb0) = u0.q;
        *(uint4*)((char*)Bl[0] + bb1) = u1.q;
    }
    __syncthreads();

    f32x4 acc[4][2] = {};
    int cur = 0;
    for (int k0 = 0; k0 < D_DIM; k0 += 64) {
        bool pf = (k0 + 64 < D_DIM);
        int nxt = cur ^ 1;
        if (pf) {                        // issue next-tile loads; fly over MFMA
            gload_lds16(ga0, (char*)Al[nxt] + wid * 2048);
            gload_lds16(ga1, (char*)Al[nxt] + wid * 2048 + 1024);
            ga0 += 128; ga1 += 128;
            #pragma unroll
            for (int i = 0; i < 16; ++i)
                pb[i] = wp[(size_t)(k0 + 64 + i) * D_DIM];
        }
        const char* Ac = (const char*)Al[cur];
        const char* Bc = (const char*)Bl[cur];
        #pragma unroll
        for (int kk = 0; kk < 2; ++kk) {
            int koff = kk * 64 + lg * 16;
            int sw = (lr & 7) << 4;
            bf16x8 af[4], bfr[2];
            #pragma unroll
            for (int mi = 0; mi < 4; ++mi)
                af[mi] = *(const bf16x8*)(Ac + (wm + mi * 16 + lr) * 128 + (koff ^ sw));
            #pragma unroll
            for (int ni = 0; ni < 2; ++ni)
                bfr[ni] = *(const bf16x8*)(Bc + (wn + ni * 16 + lr) * 128 + (koff ^ sw));
            #pragma unroll
            for (int mi = 0; mi < 4; ++mi)
                #pragma unroll
                for (int ni = 0; ni < 2; ++ni)
                    acc[mi][ni] = __builtin_amdgcn_mfma_f32_16x16x32_bf16(
                        af[mi], bfr[ni], acc[mi][ni], 0, 0, 0);
        }
        if (pf) {                        // cvt+write B(t+1) into other buffer
            Pk8 u0, u1;
            #pragma unroll
            for (int i = 0; i < 8; ++i) { u0.s[i] = f2bf(pb[i]); u1.s[i] = f2bf(pb[8 + i]); }
            *(uint4*)((char*)Bl[nxt] + bb0) = u0.q;
            *(uint4*)((char*)Bl[nxt] + bb1) = u1.q;
        }
        __syncthreads();                 // one barrier per K-step
        cur = nxt;
    }
    float bb[2];
    bb[0] = bias[gn0 + wn + lr];
    bb[1] = bias[gn0 + wn + 16 + lr];
    #pragma unroll
    for (int mi = 0; mi < 4; ++mi)
        #pragma unroll
        for (int j = 0; j < 4; ++j) {
            int rl = wm + mi * 16 + lg * 4 + j;
            if (rl < valid) {
                unsigned short* dst = scratch +
                    (size_t)(srow_base + rl) * D_DIM + gn0 + wn + lr;
                dst[0]  = f2bf(acc[mi][0][j] + bb[0]);
                dst[16] = f2bf(acc[mi][1][j] + bb[1]);
            }
        }
}

// Per-token gather-reduce: h[tok] = relu(self_row + sum of dep rows)
__global__ __launch_bounds__(256) void k_reduce(const int* __restrict__ ws,
                                                const unsigned short* __restrict__ scratch,
                                                float* __restrict__ out_h) {
    int tok = blockIdx.x;
    int t = threadIdx.x;
    int j0 = ws[17408 + tok], j1 = ws[17408 + tok + 1];
    ushort4 sv = *(const ushort4*)(scratch + (size_t)(8192 + tok) * D_DIM + t * 4);
    float a0 = bf2f(sv.x), a1 = bf2f(sv.y), a2 = bf2f(sv.z), a3 = bf2f(sv.w);
    for (int j = j0; j < j1; ++j) {
        int p = ws[22528 + j];
        ushort4 dv = *(const ushort4*)(scratch + (size_t)p * D_DIM + t * 4);
        a0 += bf2f(dv.x); a1 += bf2f(dv.y); a2 += bf2f(dv.z); a3 += bf2f(dv.w);
    }
    float4 o;
    o.x = fmaxf(a0, 0.f); o.y = fmaxf(a1, 0.f);
    o.z = fmaxf(a2, 0.f); o.w = fmaxf(a3, 0.f);
    *(float4*)(out_h + (size_t)tok * D_DIM + t * 4) = o;
}

// MFMA tag head v2: 256 blocks x 16 tokens, 4 waves k-split (256 k each),
// wave-private LDS staging (no barriers in k-loop), LDS partial reduce,
// wave-0 log-softmax epilogue.
__global__ __launch_bounds__(256) void k_tag(const float* __restrict__ out_h,
                                             const float* __restrict__ Wt,
                                             const float* __restrict__ bt,
                                             float* __restrict__ out_tag) {
    __shared__ unsigned short Abuf[4][16 * 64];   // per-wave A, 2 KB each
    __shared__ unsigned short Bbuf[4][32 * 64];   // per-wave B, 4 KB each
    __shared__ float red[4][2][256];              // partials, 8 KB
    int tok0 = blockIdx.x * 16;
    int t = threadIdx.x;
    int w = t >> 6, l = t & 63, lr = l & 15, lg = l >> 4;
    char* Ab = (char*)Abuf[w];
    char* Bb = (char*)Bbuf[w];
    int kbase = w * 256;
    int arow = l >> 2, ak = (l & 3) * 16;         // A map: 16 rows x 4 lanes
    int btag = l >> 1, bk = (l & 1) * 32;         // B map: 32 tags x 2 lanes
    f32x4 acc[2] = {};
    for (int kc = 0; kc < 4; ++kc) {
        int k0 = kbase + kc * 64;
        {   // stage A: row arow, k [ak, ak+16)
            const float* hp = out_h + (size_t)(tok0 + arow) * D_DIM + k0 + ak;
            Pk8 u0, u1;
            #pragma unroll
            for (int i = 0; i < 8; ++i) { u0.s[i] = f2bf(hp[i]); u1.s[i] = f2bf(hp[8 + i]); }
            int sw = (arow & 7) << 4;
            *(uint4*)(Ab + arow * 128 + ((ak * 2) ^ sw)) = u0.q;
            *(uint4*)(Ab + arow * 128 + ((ak * 2 + 16) ^ sw)) = u1.q;
        }
        {   // stage B: tag btag, k [bk, bk+32)
            int sw = (btag & 7) << 4;
            #pragma unroll
            for (int q = 0; q < 4; ++q) {
                Pk8 u;
                #pragma unroll
                for (int i = 0; i < 8; ++i)
                    u.s[i] = f2bf(Wt[(size_t)(k0 + bk + q * 8 + i) * T_TAG + btag]);
                *(uint4*)(Bb + btag * 128 + ((bk * 2 + q * 16) ^ sw)) = u.q;
            }
        }
        // wave-local producer->consumer: compiler inserts lgkm waits
        #pragma unroll
        for (int kk = 0; kk < 2; ++kk) {
            int koff = kk * 64 + lg * 16;
            int sw = (lr & 7) << 4;
            bf16x8 af = *(const bf16x8*)(Ab + lr * 128 + (koff ^ sw));
            #pragma unroll
            for (int ni = 0; ni < 2; ++ni) {
                bf16x8 bfr = *(const bf16x8*)(Bb + (ni * 16 + lr) * 128 + (koff ^ sw));
                acc[ni] = __builtin_amdgcn_mfma_f32_16x16x32_bf16(
                    af, bfr, acc[ni], 0, 0, 0);
            }
        }
    }
    #pragma unroll
    for (int ni = 0; ni < 2; ++ni)
        #pragma unroll
        for (int j = 0; j < 4; ++j)
            red[w][ni][j * 64 + l] = acc[ni][j];
    __syncthreads();
    if (w == 0) {
        float bt0 = bt[lr], bt1 = bt[16 + lr];
        #pragma unroll
        for (int j = 0; j < 4; ++j) {
            float v0 = red[0][0][j * 64 + l] + red[1][0][j * 64 + l] +
                       red[2][0][j * 64 + l] + red[3][0][j * 64 + l] + bt0;
            float v1 = red[0][1][j * 64 + l] + red[1][1][j * 64 + l] +
                       red[2][1][j * 64 + l] + red[3][1][j * 64 + l] + bt1;
            float m = fmaxf(v0, v1);
            #pragma unroll
            for (int s = 1; s < 16; s <<= 1) m = fmaxf(m, __shfl_xor(m, s));
            float sum = expf(v0 - m) + expf(v1 - m);
            #pragma unroll
            for (int s = 1; s < 16; s <<= 1) sum += __shfl_xor(sum, s);
            float lse = m + logf(sum);
            int row = tok0 + lg * 4 + j;
            out_tag[(size_t)row * T_TAG + lr] = v0 - lse;
            out_tag[(size_t)row * T_TAG + 16 + lr] = v1 - lse;
        }
    }
}

extern "C" void kernel_launch(void* const* d_in, const int* in_sizes, int n_in,
                              void* d_out, int out_size, void* d_ws, size_t ws_size,
                              hipStream_t stream) {
    const float* x     = (const float*)d_in[0];
    const float* Wself = (const float*)d_in[1];
    const float* bself = (const float*)d_in[2];
    const float* Wst   = (const float*)d_in[3];
    const float* Bst   = (const float*)d_in[4];
    const float* Wtag  = (const float*)d_in[5];
    const float* btag  = (const float*)d_in[6];
    const int*   etok  = (const int*)d_in[7];
    const int*   erel  = (const int*)d_in[8];
    float* out_tag = (float*)d_out;
    float* out_h   = (float*)d_out + (size_t)N_TOK * T_TAG;
    int* ws = (int*)d_ws;
    unsigned short* scratch = (unsigned short*)((int*)d_ws + 32768);
    unsigned short* xb = scratch + (size_t)12288 * 1024;

    k_prep<<<513, 1024, 0, stream>>>(erel, etok, x, ws, xb);
    k_fused<<<dim3(GRID_ITEMS, D_DIM / 128), 512, 0, stream>>>(
        Wself, bself, Wst, Bst, ws, xb, scratch);
    k_reduce<<<N_TOK, 256, 0, stream>>>(ws, scratch, out_h);
    k_tag<<<N_TOK / 16, 256, 0, stream>>>(out_h, Wtag, btag, out_tag);
}